// Round 1
// baseline (1881.031 us; speedup 1.0000x reference)
//
#include <hip/hip_runtime.h>
#include <hip/hip_bf16.h>

// ---------------------------------------------------------------------------
// EdgeClassifierGNN: 2x SAGEConv(mean) + BN + ReLU, then 3-layer edge MLP.
// Key identity: lin_l(mean(x[src])) == mean((x @ Wl.T)[src])  -> apply the
// linear BEFORE aggregation so gather/scatter is 64-wide, not 128-wide.
// ---------------------------------------------------------------------------

#define EPS 1e-5f

// out[n][f] = dot(x[n][:K], W[f][:K]) + bias[f]   (bias may be null)
template<int K>
__global__ __launch_bounds__(256) void k_lin(
    const float* __restrict__ x, const float* __restrict__ W,
    const float* __restrict__ bias, float* __restrict__ out, int N) {
  constexpr int P = K + 1;          // pad: (f*P+k)%32 = (f+k)%32 -> 2-way, free
  __shared__ float w[64 * P];
  for (int idx = threadIdx.x; idx < 64 * K; idx += 256) {
    int f = idx / K, k = idx - f * K;
    w[f * P + k] = W[idx];
  }
  __syncthreads();
  const int f  = threadIdx.x & 63;
  const int ns = threadIdx.x >> 6;
  const float bv = bias ? bias[f] : 0.f;
  for (int n = blockIdx.x * 4 + ns; n < N; n += gridDim.x * 4) {
    const float* xr = x + (size_t)n * K;
    float acc = bv;
#pragma unroll 8
    for (int k = 0; k < K; ++k) acc += xr[k] * w[f * P + k];
    out[(size_t)n * 64 + f] = acc;
  }
}

// scatter-add: s[dst[e]][f] += q[src[e]][f]; optionally count in-degree
__global__ __launch_bounds__(256) void k_scatter(
    const float* __restrict__ q, const int* __restrict__ src,
    const int* __restrict__ dst, float* __restrict__ s,
    float* __restrict__ cnt, int E, int addCnt) {
  int idx = blockIdx.x * 256 + threadIdx.x;
  int e = idx >> 6;
  int f = idx & 63;
  if (e < E) {
    int sN = src[e], dN = dst[e];
    float v = q[(size_t)sN * 64 + f];
    atomicAdd(&s[(size_t)dN * 64 + f], v);
    if (addCnt && f == 0) atomicAdd(&cnt[dN], 1.0f);
  }
}

// hpre = s/max(cnt,1) + p ; accumulate per-feature sum & sumsq into stats[0..127]
__global__ __launch_bounds__(256) void k_combine_stats(
    const float* __restrict__ s, const float* __restrict__ cnt,
    const float* __restrict__ p, float* __restrict__ hpre,
    float* __restrict__ stats, int N) {
  __shared__ float red[512];
  const int f  = threadIdx.x & 63;
  const int ns = threadIdx.x >> 6;
  float lsum = 0.f, lsq = 0.f;
  for (int n = blockIdx.x * 4 + ns; n < N; n += gridDim.x * 4) {
    float c = cnt[n];
    c = c > 1.f ? c : 1.f;
    float v = s[(size_t)n * 64 + f] / c + p[(size_t)n * 64 + f];
    hpre[(size_t)n * 64 + f] = v;
    lsum += v;
    lsq  += v * v;
  }
  red[threadIdx.x]       = lsum;
  red[256 + threadIdx.x] = lsq;
  __syncthreads();
  if (threadIdx.x < 64) {
    float ts = red[f] + red[f + 64] + red[f + 128] + red[f + 192];
    float tq = red[256 + f] + red[256 + f + 64] + red[256 + f + 128] + red[256 + f + 192];
    atomicAdd(&stats[f], ts);
    atomicAdd(&stats[64 + f], tq);
  }
}

__global__ void k_finalize(float* stats, int N) {
  int f = threadIdx.x;  // 64 threads
  float inv_n = 1.0f / (float)N;
  float mean = stats[f] * inv_n;
  float var  = stats[64 + f] * inv_n - mean * mean;
  stats[128 + f] = mean;
  stats[192 + f] = rsqrtf(var + EPS);
}

__global__ __launch_bounds__(256) void k_bnrelu(
    const float* __restrict__ hpre, const float* __restrict__ stats,
    const float* __restrict__ g, const float* __restrict__ be,
    float* __restrict__ out, int total) {
  int idx = blockIdx.x * 256 + threadIdx.x;
  if (idx < total) {
    int f = idx & 63;
    float v = (hpre[idx] - stats[128 + f]) * stats[192 + f] * g[f] + be[f];
    out[idx] = v > 0.f ? v : 0.f;
  }
}

__global__ void k_transpose(const float* __restrict__ W, float* __restrict__ WT,
                            int R, int C) {
  int idx = blockIdx.x * 256 + threadIdx.x;
  if (idx < R * C) {
    int r = idx / C, c = idx - r * C;
    WT[c * R + r] = W[r * C + c];
  }
}

// Fused edge MLP: per 32-edge tile. in=[h[src](64) | attr(16) | h[dst](64)]=144
// z1 = relu(in @ Wt1 + bm1) [128]; z2 = relu(z1 @ Wt2 + bm2) [64]; out = z2 @ Wm3.T + bm3 [2]
__global__ __launch_bounds__(256) void k_mlp(
    const float* __restrict__ h, const float* __restrict__ attr,
    const int* __restrict__ src, const int* __restrict__ dst,
    const float* __restrict__ Wt1, const float* __restrict__ bm1,
    const float* __restrict__ Wt2, const float* __restrict__ bm2,
    const float* __restrict__ Wm3, const float* __restrict__ bm3,
    float* __restrict__ out, int E) {
  __shared__ __align__(16) float Elds[32][148];   // 18944 B (pad 144->148)
  __shared__ __align__(16) float Bst[16 * 128];   //  8192 B (weight k-chunk)
  __shared__ __align__(16) float Z1[32][132];     // 16896 B (pad 128->132)
  __shared__ __align__(16) float Z2[32][68];      //  8704 B (pad 64->68)
  const int tid = threadIdx.x;
  const int e0  = blockIdx.x * 32;

  // ---- gather edge inputs to LDS ----
  for (int idx = tid; idx < 32 * 144; idx += 256) {
    int e = idx / 144, k = idx - e * 144;
    int ge = e0 + e;
    float v = 0.f;
    if (ge < E) {
      if (k < 64)       v = h[(size_t)src[ge] * 64 + k];
      else if (k < 80)  v = attr[(size_t)ge * 16 + (k - 64)];
      else              v = h[(size_t)dst[ge] * 64 + (k - 80)];
    }
    Elds[e][k] = v;
  }
  __syncthreads();

  // ---- layer 1: [32 x 128], K=144 ----
  {
    const int tx = tid & 31;   // cols 4*tx..4*tx+3
    const int ty = tid >> 5;   // edges 4*ty..4*ty+3
    float acc[4][4];
#pragma unroll
    for (int i = 0; i < 4; ++i)
#pragma unroll
      for (int c = 0; c < 4; ++c) acc[i][c] = bm1[4 * tx + c];
    for (int kc = 0; kc < 144; kc += 16) {
#pragma unroll
      for (int l = 0; l < 8; ++l) Bst[tid + l * 256] = Wt1[(size_t)kc * 128 + tid + l * 256];
      __syncthreads();
#pragma unroll
      for (int kk = 0; kk < 16; kk += 4) {
        float4 a[4], b[4];
#pragma unroll
        for (int i = 0; i < 4; ++i) a[i] = *(const float4*)&Elds[4 * ty + i][kc + kk];
#pragma unroll
        for (int u = 0; u < 4; ++u) b[u] = *(const float4*)&Bst[(kk + u) * 128 + 4 * tx];
#pragma unroll
        for (int i = 0; i < 4; ++i) {
#pragma unroll
          for (int u = 0; u < 4; ++u) {
            float av = (u == 0) ? a[i].x : (u == 1) ? a[i].y : (u == 2) ? a[i].z : a[i].w;
            acc[i][0] += av * b[u].x;
            acc[i][1] += av * b[u].y;
            acc[i][2] += av * b[u].z;
            acc[i][3] += av * b[u].w;
          }
        }
      }
      __syncthreads();
    }
#pragma unroll
    for (int i = 0; i < 4; ++i) {
      float4 r;
      r.x = fmaxf(acc[i][0], 0.f); r.y = fmaxf(acc[i][1], 0.f);
      r.z = fmaxf(acc[i][2], 0.f); r.w = fmaxf(acc[i][3], 0.f);
      *(float4*)&Z1[4 * ty + i][4 * tx] = r;
    }
  }
  __syncthreads();

  // ---- layer 2: [32 x 64], K=128 ----
  {
    const int tx = tid & 15;   // cols 4*tx..4*tx+3
    const int ty = tid >> 4;   // edges 2*ty..2*ty+1
    float acc[2][4];
#pragma unroll
    for (int i = 0; i < 2; ++i)
#pragma unroll
      for (int c = 0; c < 4; ++c) acc[i][c] = bm2[4 * tx + c];
    for (int kc = 0; kc < 128; kc += 16) {
#pragma unroll
      for (int l = 0; l < 4; ++l) Bst[tid + l * 256] = Wt2[(size_t)kc * 64 + tid + l * 256];
      __syncthreads();
#pragma unroll
      for (int kk = 0; kk < 16; kk += 4) {
        float4 a[2], b[4];
#pragma unroll
        for (int i = 0; i < 2; ++i) a[i] = *(const float4*)&Z1[2 * ty + i][kc + kk];
#pragma unroll
        for (int u = 0; u < 4; ++u) b[u] = *(const float4*)&Bst[(kk + u) * 64 + 4 * tx];
#pragma unroll
        for (int i = 0; i < 2; ++i) {
#pragma unroll
          for (int u = 0; u < 4; ++u) {
            float av = (u == 0) ? a[i].x : (u == 1) ? a[i].y : (u == 2) ? a[i].z : a[i].w;
            acc[i][0] += av * b[u].x;
            acc[i][1] += av * b[u].y;
            acc[i][2] += av * b[u].z;
            acc[i][3] += av * b[u].w;
          }
        }
      }
      __syncthreads();
    }
#pragma unroll
    for (int i = 0; i < 2; ++i) {
      float4 r;
      r.x = fmaxf(acc[i][0], 0.f); r.y = fmaxf(acc[i][1], 0.f);
      r.z = fmaxf(acc[i][2], 0.f); r.w = fmaxf(acc[i][3], 0.f);
      *(float4*)&Z2[2 * ty + i][4 * tx] = r;
    }
  }
  __syncthreads();

  // ---- layer 3: [32 x 2], K=64 ----
  if (tid < 64) {
    int e = tid >> 1, o = tid & 1;
    float acc = bm3[o];
#pragma unroll 8
    for (int k = 0; k < 64; ++k) acc += Z2[e][k] * Wm3[o * 64 + k];
    if (e0 + e < E) out[(size_t)(e0 + e) * 2 + o] = acc;
  }
}

extern "C" void kernel_launch(void* const* d_in, const int* in_sizes, int n_in,
                              void* d_out, int out_size, void* d_ws, size_t ws_size,
                              hipStream_t stream) {
  const float* x    = (const float*)d_in[0];
  const int*   ei   = (const int*)d_in[1];
  const float* attr = (const float*)d_in[2];
  const float* W1l  = (const float*)d_in[3];
  const float* b1l  = (const float*)d_in[4];
  const float* W1r  = (const float*)d_in[5];
  const float* g1   = (const float*)d_in[6];
  const float* be1  = (const float*)d_in[7];
  const float* W2l  = (const float*)d_in[8];
  const float* b2l  = (const float*)d_in[9];
  const float* W2r  = (const float*)d_in[10];
  const float* g2   = (const float*)d_in[11];
  const float* be2  = (const float*)d_in[12];
  const float* Wm1  = (const float*)d_in[13];
  const float* bm1  = (const float*)d_in[14];
  const float* Wm2  = (const float*)d_in[15];
  const float* bm2  = (const float*)d_in[16];
  const float* Wm3  = (const float*)d_in[17];
  const float* bm3  = (const float*)d_in[18];
  float* out = (float*)d_out;

  const int N = in_sizes[0] / 128;
  const int E = in_sizes[1] / 2;
  const int* srcI = ei;
  const int* dstI = ei + E;

  float* ws = (float*)d_ws;
  const size_t NF = (size_t)N * 64;
  float* A      = ws;            // q (post-Wl features, pre-aggregation)
  float* B      = A + NF;        // p / h
  float* C      = B + NF;        // s1 / p2
  float* D      = C + NF;        // s2
  float* cnt    = D + NF;        // [N]
  float* stats1 = cnt + N;       // [256]: sum, sumsq, mean, invstd
  float* stats2 = stats1 + 256;  // [256]
  float* Wt1    = stats2 + 256;  // [144*128]
  float* Wt2    = Wt1 + 144 * 128;  // [128*64]

  hipMemsetAsync(C, 0, NF * sizeof(float), stream);
  hipMemsetAsync(D, 0, NF * sizeof(float), stream);
  hipMemsetAsync(cnt, 0, (size_t)N * sizeof(float), stream);
  hipMemsetAsync(stats1, 0, 512 * sizeof(float), stream);

  k_transpose<<<(128 * 144 + 255) / 256, 256, 0, stream>>>(Wm1, Wt1, 128, 144);
  k_transpose<<<(64 * 128 + 255) / 256, 256, 0, stream>>>(Wm2, Wt2, 64, 128);

  const int scatterBlocks = (int)(((size_t)E * 64 + 255) / 256);
  const int bnBlocks      = (int)((NF + 255) / 256);

  // ---- conv1 ----
  k_lin<128><<<512, 256, 0, stream>>>(x, W1l, nullptr, A, N);
  k_lin<128><<<512, 256, 0, stream>>>(x, W1r, b1l, B, N);
  k_scatter<<<scatterBlocks, 256, 0, stream>>>(A, srcI, dstI, C, cnt, E, 1);
  k_combine_stats<<<512, 256, 0, stream>>>(C, cnt, B, A, stats1, N);
  k_finalize<<<1, 64, 0, stream>>>(stats1, N);
  k_bnrelu<<<bnBlocks, 256, 0, stream>>>(A, stats1, g1, be1, B, (int)NF);

  // ---- conv2 (in-degree counts unchanged; reuse cnt) ----
  k_lin<64><<<512, 256, 0, stream>>>(B, W2l, nullptr, A, N);
  k_lin<64><<<512, 256, 0, stream>>>(B, W2r, b2l, C, N);
  k_scatter<<<scatterBlocks, 256, 0, stream>>>(A, srcI, dstI, D, cnt, E, 0);
  k_combine_stats<<<512, 256, 0, stream>>>(D, cnt, C, A, stats2, N);
  k_finalize<<<1, 64, 0, stream>>>(stats2, N);
  k_bnrelu<<<bnBlocks, 256, 0, stream>>>(A, stats2, g2, be2, B, (int)NF);

  // ---- edge MLP ----
  k_mlp<<<(E + 31) / 32, 256, 0, stream>>>(B, attr, srcI, dstI, Wt1, bm1, Wt2, bm2,
                                           Wm3, bm3, out, E);
}

// Round 2
// 1663.270 us; speedup vs baseline: 1.1309x; 1.1309x over previous
//
#include <hip/hip_runtime.h>
#include <hip/hip_bf16.h>

// ---------------------------------------------------------------------------
// EdgeClassifierGNN: 2x SAGEConv(mean)+BN+ReLU, then 3-layer edge MLP.
// Trick 1: lin_l before mean-aggregation (64-wide scatter).
// Trick 2: edge-MLP layer 1 split: z1 = relu(u[src] + v[dst] + B1*attr),
//          u[n]=A1*h[n]+bm1, v[n]=C1*h[n] precomputed per NODE (A1,B1,C1 are
//          column slices of Wm1). Removes 77% of per-edge FLOPs.
// ---------------------------------------------------------------------------

#define EPS 1e-5f

// out[n][f] = dot(x[n][:K], W[f][:K]) + bias[f]   (bias may be null)
template<int K>
__global__ __launch_bounds__(256) void k_lin(
    const float* __restrict__ x, const float* __restrict__ W,
    const float* __restrict__ bias, float* __restrict__ out, int N) {
  constexpr int P = K + 1;
  __shared__ float w[64 * P];
  for (int idx = threadIdx.x; idx < 64 * K; idx += 256) {
    int f = idx / K, k = idx - f * K;
    w[f * P + k] = W[idx];
  }
  __syncthreads();
  const int f  = threadIdx.x & 63;
  const int ns = threadIdx.x >> 6;
  const float bv = bias ? bias[f] : 0.f;
  for (int n = blockIdx.x * 4 + ns; n < N; n += gridDim.x * 4) {
    const float* xr = x + (size_t)n * K;
    float acc = bv;
#pragma unroll 8
    for (int k = 0; k < K; ++k) acc += xr[k] * w[f * P + k];
    out[(size_t)n * 64 + f] = acc;
  }
}

// out[n][c] = (bias?bias[c]:0) + sum_{k<64} h[n][k] * W[c*144 + off + k], c<128
__global__ __launch_bounds__(256) void k_lin2(
    const float* __restrict__ h, const float* __restrict__ W, int off,
    const float* __restrict__ bias, float* __restrict__ out, int N) {
  __shared__ float w[128 * 65];
  for (int idx = threadIdx.x; idx < 128 * 64; idx += 256) {
    int c = idx >> 6, k = idx & 63;
    w[c * 65 + k] = W[c * 144 + off + k];
  }
  __syncthreads();
  const int c  = threadIdx.x & 127;
  const int ns = threadIdx.x >> 7;
  const float bv = bias ? bias[c] : 0.f;
  for (int n = blockIdx.x * 2 + ns; n < N; n += gridDim.x * 2) {
    const float* hr = h + (size_t)n * 64;
    float acc = bv;
#pragma unroll 8
    for (int k = 0; k < 64; ++k) acc += hr[k] * w[c * 65 + k];
    out[(size_t)n * 128 + c] = acc;
  }
}

// scatter-add (float2 per thread): s[dst[e]][f..f+1] += q[src[e]][f..f+1]
__global__ __launch_bounds__(256) void k_scatter2(
    const float* __restrict__ q, const int* __restrict__ src,
    const int* __restrict__ dst, float* __restrict__ s,
    float* __restrict__ cnt, int E, int addCnt) {
  int idx = blockIdx.x * 256 + threadIdx.x;
  int e  = idx >> 5;
  int f2 = (idx & 31) * 2;
  if (e < E) {
    int sN = src[e], dN = dst[e];
    const float2 v = *(const float2*)&q[(size_t)sN * 64 + f2];
    atomicAdd(&s[(size_t)dN * 64 + f2], v.x);
    atomicAdd(&s[(size_t)dN * 64 + f2 + 1], v.y);
    if (addCnt && f2 == 0) atomicAdd(&cnt[dN], 1.0f);
  }
}

// hpre = s/max(cnt,1) + p ; per-feature sum & sumsq into stats[0..127]
__global__ __launch_bounds__(256) void k_combine_stats(
    const float* __restrict__ s, const float* __restrict__ cnt,
    const float* __restrict__ p, float* __restrict__ hpre,
    float* __restrict__ stats, int N) {
  __shared__ float red[512];
  const int f  = threadIdx.x & 63;
  const int ns = threadIdx.x >> 6;
  float lsum = 0.f, lsq = 0.f;
  for (int n = blockIdx.x * 4 + ns; n < N; n += gridDim.x * 4) {
    float c = cnt[n];
    c = c > 1.f ? c : 1.f;
    float v = s[(size_t)n * 64 + f] / c + p[(size_t)n * 64 + f];
    hpre[(size_t)n * 64 + f] = v;
    lsum += v;
    lsq  += v * v;
  }
  red[threadIdx.x]       = lsum;
  red[256 + threadIdx.x] = lsq;
  __syncthreads();
  if (threadIdx.x < 64) {
    float ts = red[f] + red[f + 64] + red[f + 128] + red[f + 192];
    float tq = red[256 + f] + red[256 + f + 64] + red[256 + f + 128] + red[256 + f + 192];
    atomicAdd(&stats[f], ts);
    atomicAdd(&stats[64 + f], tq);
  }
}

__global__ void k_finalize(float* stats, int N) {
  int f = threadIdx.x;  // 64 threads
  float inv_n = 1.0f / (float)N;
  float mean = stats[f] * inv_n;
  float var  = stats[64 + f] * inv_n - mean * mean;
  stats[128 + f] = mean;
  stats[192 + f] = rsqrtf(var + EPS);
}

__global__ __launch_bounds__(256) void k_bnrelu(
    const float* __restrict__ hpre, const float* __restrict__ stats,
    const float* __restrict__ g, const float* __restrict__ be,
    float* __restrict__ out, int total) {
  int idx = blockIdx.x * 256 + threadIdx.x;
  if (idx < total) {
    int f = idx & 63;
    float v = (hpre[idx] - stats[128 + f]) * stats[192 + f] * g[f] + be[f];
    out[idx] = v > 0.f ? v : 0.f;
  }
}

// WT[c*R+r] = W[r*C+c]
__global__ void k_transpose(const float* __restrict__ W, float* __restrict__ WT,
                            int R, int C) {
  int idx = blockIdx.x * 256 + threadIdx.x;
  if (idx < R * C) {
    int r = idx / C, c = idx - r * C;
    WT[c * R + r] = W[r * C + c];
  }
}

// BT[k*128+c] = Wm1[c*144 + 64 + k], k<16, c<128
__global__ void k_tbt(const float* __restrict__ Wm1, float* __restrict__ BT) {
  int idx = blockIdx.x * 256 + threadIdx.x;
  if (idx < 16 * 128) {
    int k = idx >> 7, c = idx & 127;
    BT[idx] = Wm1[c * 144 + 64 + k];
  }
}

// ---------------------------------------------------------------------------
// Fused edge MLP. Per 64-edge tile:
//   z1[e][c] = relu(u[src[e]][c] + v[dst[e]][c] + sum_k attr[e][k]*BT[k][c])
//   z2 = relu(z1 @ W2T + bm2) ; out = z2 @ Wm3.T + bm3 (fused via LDS atomics)
// W2T staged in LDS once per block (persistent tile loop); BT in registers.
// LDS = 32768 + 33792 + 4096 + 512 + 512 = 71680 B -> 2 blocks/CU.
// ---------------------------------------------------------------------------
__global__ __launch_bounds__(256, 2) void k_edge(
    const float* __restrict__ u, const float* __restrict__ v,
    const float* __restrict__ attr,
    const int* __restrict__ src, const int* __restrict__ dst,
    const float* __restrict__ W2Tws, const float* __restrict__ BTws,
    const float* __restrict__ bm2, const float* __restrict__ Wm3,
    const float* __restrict__ bm3, float* __restrict__ out, int E) {
  __shared__ __align__(16) float W2Tl[128 * 64];   // [k][j]
  __shared__ __align__(16) float Z1[64 * 132];     // [e][c], pad 128->132
  __shared__ __align__(16) float attrL[64 * 16];   // [e][k]
  __shared__ int   idxL[128];                      // src[0:64], dst[64:128]
  __shared__ float outT[128];                      // [e][o]

  const int tid = threadIdx.x;
  const int c4  = tid & 31;          // assembly col-chunk (fixed per thread)
  const int tx  = tid & 15;          // layer2 col group (4 cols)
  const int ty  = tid >> 4;          // layer2 edge group (4 edges)

  // stage W2T once per block
  for (int i = tid; i < 2048; i += 256)
    ((float4*)W2Tl)[i] = ((const float4*)W2Tws)[i];

  const float4* u4 = (const float4*)u;
  const float4* v4 = (const float4*)v;
  const float4* at4 = (const float4*)attr;
  const float4* bt4 = (const float4*)BTws;

  const int nt = (E + 63) >> 6;
  for (int t = blockIdx.x; t < nt; t += gridDim.x) {
    const int e0 = t << 6;
    __syncthreads();   // protect LDS vs previous iteration (and W2T staging)

    // ---- stage indices, attr tile, init out accumulator ----
    if (tid < 64)       idxL[tid] = (e0 + tid < E) ? src[e0 + tid] : 0;
    else if (tid < 128) idxL[tid] = (e0 + tid - 64 < E) ? dst[e0 + tid - 64] : 0;
    if (tid < 128) outT[tid] = bm3[tid & 1];
    {
      int a0 = e0 * 4 + tid;                       // float4 index into attr
      float4 av = make_float4(0.f, 0.f, 0.f, 0.f);
      if (a0 < E * 4) av = at4[a0];
      ((float4*)attrL)[tid] = av;
    }
    // BT chunk for this thread's 4 columns (reload per tile: short live range)
    float4 breg[16];
#pragma unroll
    for (int k = 0; k < 16; ++k) breg[k] = bt4[k * 32 + c4];
    __syncthreads();

    // ---- layer 1 assembly: 64 edges x 32 float4-chunks ----
#pragma unroll
    for (int it = 0; it < 8; ++it) {
      const int e = it * 8 + (tid >> 5);
      const int col = c4 * 4;
      float4 a = u4[(size_t)idxL[e] * 32 + c4];
      float4 b = v4[(size_t)idxL[64 + e] * 32 + c4];
      float sx = a.x + b.x, sy = a.y + b.y, sz = a.z + b.z, sw = a.w + b.w;
#pragma unroll
      for (int k = 0; k < 16; ++k) {
        float av = attrL[e * 16 + k];
        sx += av * breg[k].x; sy += av * breg[k].y;
        sz += av * breg[k].z; sw += av * breg[k].w;
      }
      float4 r;
      r.x = fmaxf(sx, 0.f); r.y = fmaxf(sy, 0.f);
      r.z = fmaxf(sz, 0.f); r.w = fmaxf(sw, 0.f);
      *(float4*)&Z1[e * 132 + col] = r;
    }
    __syncthreads();

    // ---- layer 2: [64 edges x 64 cols], K=128, 4x4 per thread ----
    float acc[4][4];
#pragma unroll
    for (int c = 0; c < 4; ++c) {
      float bv = bm2[4 * tx + c];
#pragma unroll
      for (int i = 0; i < 4; ++i) acc[i][c] = bv;
    }
    for (int kk = 0; kk < 128; kk += 4) {
      float4 a[4], b[4];
#pragma unroll
      for (int i = 0; i < 4; ++i) a[i] = *(const float4*)&Z1[(4 * ty + i) * 132 + kk];
#pragma unroll
      for (int q = 0; q < 4; ++q) b[q] = *(const float4*)&W2Tl[(kk + q) * 64 + 4 * tx];
#pragma unroll
      for (int i = 0; i < 4; ++i) {
#pragma unroll
        for (int q = 0; q < 4; ++q) {
          float av = (q == 0) ? a[i].x : (q == 1) ? a[i].y : (q == 2) ? a[i].z : a[i].w;
          acc[i][0] += av * b[q].x;
          acc[i][1] += av * b[q].y;
          acc[i][2] += av * b[q].z;
          acc[i][3] += av * b[q].w;
        }
      }
    }

    // ---- fused layer 3: relu(z2) -> partial dot with Wm3, LDS atomics ----
    float w30[4], w31[4];
#pragma unroll
    for (int c = 0; c < 4; ++c) {
      w30[c] = Wm3[4 * tx + c];
      w31[c] = Wm3[64 + 4 * tx + c];
    }
#pragma unroll
    for (int i = 0; i < 4; ++i) {
      float p0 = 0.f, p1 = 0.f;
#pragma unroll
      for (int c = 0; c < 4; ++c) {
        float z = fmaxf(acc[i][c], 0.f);
        p0 += z * w30[c];
        p1 += z * w31[c];
      }
      atomicAdd(&outT[(4 * ty + i) * 2 + 0], p0);
      atomicAdd(&outT[(4 * ty + i) * 2 + 1], p1);
    }
    __syncthreads();

    if (tid < 128) {
      int e = tid >> 1;
      if (e0 + e < E) out[(size_t)(e0 + e) * 2 + (tid & 1)] = outT[tid];
    }
  }
}

extern "C" void kernel_launch(void* const* d_in, const int* in_sizes, int n_in,
                              void* d_out, int out_size, void* d_ws, size_t ws_size,
                              hipStream_t stream) {
  const float* x    = (const float*)d_in[0];
  const int*   ei   = (const int*)d_in[1];
  const float* attr = (const float*)d_in[2];
  const float* W1l  = (const float*)d_in[3];
  const float* b1l  = (const float*)d_in[4];
  const float* W1r  = (const float*)d_in[5];
  const float* g1   = (const float*)d_in[6];
  const float* be1  = (const float*)d_in[7];
  const float* W2l  = (const float*)d_in[8];
  const float* b2l  = (const float*)d_in[9];
  const float* W2r  = (const float*)d_in[10];
  const float* g2   = (const float*)d_in[11];
  const float* be2  = (const float*)d_in[12];
  const float* Wm1  = (const float*)d_in[13];
  const float* bm1  = (const float*)d_in[14];
  const float* Wm2  = (const float*)d_in[15];
  const float* bm2  = (const float*)d_in[16];
  const float* Wm3  = (const float*)d_in[17];
  const float* bm3  = (const float*)d_in[18];
  float* out = (float*)d_out;

  const int N = in_sizes[0] / 128;
  const int E = in_sizes[1] / 2;
  const int* srcI = ei;
  const int* dstI = ei + E;

  float* ws = (float*)d_ws;
  const size_t NF = (size_t)N * 64;
  float* P0     = ws;             // NF
  float* P1     = ws + NF;        // NF
  float* P2     = ws + 2 * NF;    // NF
  float* V      = ws + 3 * NF;    // 2*NF  (v)
  float* cnt    = ws + 5 * NF;    // N
  float* stats1 = cnt + N;        // 256
  float* stats2 = stats1 + 256;   // 256
  float* W2Tws  = stats2 + 256;   // 128*64
  float* BTws   = W2Tws + 8192;   // 16*128
  float* U      = ws;             // 2*NF (overlays P0,P1 — free by then)

  hipMemsetAsync(P2, 0, NF * sizeof(float), stream);
  hipMemsetAsync(cnt, 0, (size_t)N * sizeof(float), stream);
  hipMemsetAsync(stats1, 0, 512 * sizeof(float), stream);

  k_transpose<<<(64 * 128 + 255) / 256, 256, 0, stream>>>(Wm2, W2Tws, 64, 128);
  k_tbt<<<(16 * 128 + 255) / 256, 256, 0, stream>>>(Wm1, BTws);

  const int scatterBlocks = (int)(((size_t)E * 32 + 255) / 256);
  const int bnBlocks      = (int)((NF + 255) / 256);

  // ---- conv1 ----
  k_lin<128><<<512, 256, 0, stream>>>(x, W1l, nullptr, P0, N);   // q1
  k_lin<128><<<512, 256, 0, stream>>>(x, W1r, b1l, P1, N);       // p1
  k_scatter2<<<scatterBlocks, 256, 0, stream>>>(P0, srcI, dstI, P2, cnt, E, 1);
  k_combine_stats<<<512, 256, 0, stream>>>(P2, cnt, P1, P0, stats1, N);  // hpre1
  k_finalize<<<1, 64, 0, stream>>>(stats1, N);
  k_bnrelu<<<bnBlocks, 256, 0, stream>>>(P0, stats1, g1, be1, P1, (int)NF);  // h1

  // ---- conv2 ----
  k_lin<64><<<512, 256, 0, stream>>>(P1, W2l, nullptr, P0, N);   // q2
  k_lin<64><<<512, 256, 0, stream>>>(P1, W2r, b2l, P2, N);       // p2
  hipMemsetAsync(P1, 0, NF * sizeof(float), stream);             // s2
  k_scatter2<<<scatterBlocks, 256, 0, stream>>>(P0, srcI, dstI, P1, cnt, E, 0);
  k_combine_stats<<<512, 256, 0, stream>>>(P1, cnt, P2, P0, stats2, N);  // hpre2
  k_finalize<<<1, 64, 0, stream>>>(stats2, N);
  k_bnrelu<<<bnBlocks, 256, 0, stream>>>(P0, stats2, g2, be2, P2, (int)NF);  // h2

  // ---- per-node u/v for edge-MLP layer 1 ----
  k_lin2<<<1024, 256, 0, stream>>>(P2, Wm1, 0,  bm1,     U, N);  // u = A1*h+bm1
  k_lin2<<<1024, 256, 0, stream>>>(P2, Wm1, 80, nullptr, V, N);  // v = C1*h

  // ---- fused edge MLP ----
  k_edge<<<512, 256, 0, stream>>>(U, V, attr, srcI, dstI, W2Tws, BTws,
                                  bm2, Wm3, bm3, out, E);
}

// Round 3
// 1346.395 us; speedup vs baseline: 1.3971x; 1.2354x over previous
//
#include <hip/hip_runtime.h>
#include <hip/hip_bf16.h>

// ---------------------------------------------------------------------------
// EdgeClassifierGNN: 2x SAGEConv(mean)+BN+ReLU, then 3-layer edge MLP.
// Trick 1: lin_l before mean-aggregation (64-wide gather).
// Trick 2: edge-MLP layer 1 split: z1 = relu(u[src] + v[dst] + B1*attr).
// Trick 3 (this round): build CSR (dst-sorted) once per call; aggregation is
//          an atomic-free per-node gather fused with mean + residual + BN stats.
// ---------------------------------------------------------------------------

#define EPS 1e-5f

// out[n][f] = dot(x[n][:K], W[f][:K]) + bias[f]   (bias may be null)
template<int K>
__global__ __launch_bounds__(256) void k_lin(
    const float* __restrict__ x, const float* __restrict__ W,
    const float* __restrict__ bias, float* __restrict__ out, int N) {
  constexpr int P = K + 1;
  __shared__ float w[64 * P];
  for (int idx = threadIdx.x; idx < 64 * K; idx += 256) {
    int f = idx / K, k = idx - f * K;
    w[f * P + k] = W[idx];
  }
  __syncthreads();
  const int f  = threadIdx.x & 63;
  const int ns = threadIdx.x >> 6;
  const float bv = bias ? bias[f] : 0.f;
  for (int n = blockIdx.x * 4 + ns; n < N; n += gridDim.x * 4) {
    const float* xr = x + (size_t)n * K;
    float acc = bv;
#pragma unroll 8
    for (int k = 0; k < K; ++k) acc += xr[k] * w[f * P + k];
    out[(size_t)n * 64 + f] = acc;
  }
}

// out[n][c] = (bias?bias[c]:0) + sum_{k<64} h[n][k] * W[c*144 + off + k], c<128
__global__ __launch_bounds__(256) void k_lin2(
    const float* __restrict__ h, const float* __restrict__ W, int off,
    const float* __restrict__ bias, float* __restrict__ out, int N) {
  __shared__ float w[128 * 65];
  for (int idx = threadIdx.x; idx < 128 * 64; idx += 256) {
    int c = idx >> 6, k = idx & 63;
    w[c * 65 + k] = W[c * 144 + off + k];
  }
  __syncthreads();
  const int c  = threadIdx.x & 127;
  const int ns = threadIdx.x >> 7;
  const float bv = bias ? bias[c] : 0.f;
  for (int n = blockIdx.x * 2 + ns; n < N; n += gridDim.x * 2) {
    const float* hr = h + (size_t)n * 64;
    float acc = bv;
#pragma unroll 8
    for (int k = 0; k < 64; ++k) acc += hr[k] * w[c * 65 + k];
    out[(size_t)n * 128 + c] = acc;
  }
}

// ---------------- CSR build ----------------
__global__ __launch_bounds__(256) void k_hist(
    const int* __restrict__ dst, int* __restrict__ deg, int E) {
  int e = blockIdx.x * 256 + threadIdx.x;
  if (e < E) atomicAdd(&deg[dst[e]], 1);
}

// single-block exclusive scan (N up to ~10^6 is fine: N/1024 iters x 10 steps)
__global__ __launch_bounds__(1024) void k_scan(
    const int* __restrict__ deg, int* __restrict__ rowptr,
    int* __restrict__ cursor, int N) {
  __shared__ int buf[1024];
  __shared__ int carry;
  if (threadIdx.x == 0) carry = 0;
  __syncthreads();
  for (int base = 0; base < N; base += 1024) {
    int i = base + threadIdx.x;
    int v = (i < N) ? deg[i] : 0;
    buf[threadIdx.x] = v;
    __syncthreads();
    for (int off = 1; off < 1024; off <<= 1) {
      int t = (threadIdx.x >= off) ? buf[threadIdx.x - off] : 0;
      __syncthreads();
      buf[threadIdx.x] += t;
      __syncthreads();
    }
    int incl = buf[threadIdx.x];
    int c = carry;
    if (i < N) { rowptr[i] = c + incl - v; cursor[i] = c + incl - v; }
    __syncthreads();
    if (threadIdx.x == 1023) carry = c + buf[1023];
    __syncthreads();
  }
  if (threadIdx.x == 0) rowptr[N] = carry;
}

__global__ __launch_bounds__(256) void k_fill(
    const int* __restrict__ src, const int* __restrict__ dst,
    int* __restrict__ cursor, int* __restrict__ csr_src, int E) {
  int e = blockIdx.x * 256 + threadIdx.x;
  if (e < E) {
    int pos = atomicAdd(&cursor[dst[e]], 1);
    csr_src[pos] = src[e];
  }
}

// ---------------- fused aggregate + mean + residual + BN stats ----------------
// hpre[n][f] = (sum_{j in row n} q[csr_src[j]][f]) / max(deg,1) + p[n][f]
// stats[0..63] += sum_f, stats[64..127] += sumsq_f
__global__ __launch_bounds__(256) void k_agg(
    const float* __restrict__ q, const float* __restrict__ p,
    const int* __restrict__ rowptr, const int* __restrict__ csr_src,
    float* __restrict__ hpre, float* __restrict__ stats, int N) {
  __shared__ float red[512];
  const int f  = threadIdx.x & 63;
  const int ns = threadIdx.x >> 6;
  float lsum = 0.f, lsq = 0.f;
  for (int n = blockIdx.x * 4 + ns; n < N; n += gridDim.x * 4) {
    const int r0 = rowptr[n], r1 = rowptr[n + 1];
    float s0 = 0.f, s1 = 0.f;
    int j = r0;
    for (; j + 1 < r1; j += 2) {
      int a = csr_src[j], b = csr_src[j + 1];
      s0 += q[(size_t)a * 64 + f];
      s1 += q[(size_t)b * 64 + f];
    }
    if (j < r1) s0 += q[(size_t)csr_src[j] * 64 + f];
    float c = (float)(r1 - r0);
    c = c > 1.f ? c : 1.f;
    float v = (s0 + s1) / c + p[(size_t)n * 64 + f];
    hpre[(size_t)n * 64 + f] = v;
    lsum += v;
    lsq  += v * v;
  }
  red[threadIdx.x]       = lsum;
  red[256 + threadIdx.x] = lsq;
  __syncthreads();
  if (threadIdx.x < 64) {
    float ts = red[f] + red[f + 64] + red[f + 128] + red[f + 192];
    float tq = red[256 + f] + red[256 + f + 64] + red[256 + f + 128] + red[256 + f + 192];
    atomicAdd(&stats[f], ts);
    atomicAdd(&stats[64 + f], tq);
  }
}

__global__ void k_finalize(float* stats, int N) {
  int f = threadIdx.x;  // 64 threads
  float inv_n = 1.0f / (float)N;
  float mean = stats[f] * inv_n;
  float var  = stats[64 + f] * inv_n - mean * mean;
  stats[128 + f] = mean;
  stats[192 + f] = rsqrtf(var + EPS);
}

__global__ __launch_bounds__(256) void k_bnrelu(
    const float* __restrict__ hpre, const float* __restrict__ stats,
    const float* __restrict__ g, const float* __restrict__ be,
    float* __restrict__ out, int total) {
  int idx = blockIdx.x * 256 + threadIdx.x;
  if (idx < total) {
    int f = idx & 63;
    float v = (hpre[idx] - stats[128 + f]) * stats[192 + f] * g[f] + be[f];
    out[idx] = v > 0.f ? v : 0.f;
  }
}

// WT[c*R+r] = W[r*C+c]
__global__ void k_transpose(const float* __restrict__ W, float* __restrict__ WT,
                            int R, int C) {
  int idx = blockIdx.x * 256 + threadIdx.x;
  if (idx < R * C) {
    int r = idx / C, c = idx - r * C;
    WT[c * R + r] = W[r * C + c];
  }
}

// BT[k*128+c] = Wm1[c*144 + 64 + k], k<16, c<128
__global__ void k_tbt(const float* __restrict__ Wm1, float* __restrict__ BT) {
  int idx = blockIdx.x * 256 + threadIdx.x;
  if (idx < 16 * 128) {
    int k = idx >> 7, c = idx & 127;
    BT[idx] = Wm1[c * 144 + 64 + k];
  }
}

// ---------------------------------------------------------------------------
// Fused edge MLP (unchanged from round 2). Per 64-edge tile:
//   z1[e][c] = relu(u[src[e]][c] + v[dst[e]][c] + sum_k attr[e][k]*BT[k][c])
//   z2 = relu(z1 @ W2T + bm2) ; out = z2 @ Wm3.T + bm3 (fused via LDS atomics)
// ---------------------------------------------------------------------------
__global__ __launch_bounds__(256, 2) void k_edge(
    const float* __restrict__ u, const float* __restrict__ v,
    const float* __restrict__ attr,
    const int* __restrict__ src, const int* __restrict__ dst,
    const float* __restrict__ W2Tws, const float* __restrict__ BTws,
    const float* __restrict__ bm2, const float* __restrict__ Wm3,
    const float* __restrict__ bm3, float* __restrict__ out, int E) {
  __shared__ __align__(16) float W2Tl[128 * 64];   // [k][j]
  __shared__ __align__(16) float Z1[64 * 132];     // [e][c], pad 128->132
  __shared__ __align__(16) float attrL[64 * 16];   // [e][k]
  __shared__ int   idxL[128];                      // src[0:64], dst[64:128]
  __shared__ float outT[128];                      // [e][o]

  const int tid = threadIdx.x;
  const int c4  = tid & 31;
  const int tx  = tid & 15;
  const int ty  = tid >> 4;

  for (int i = tid; i < 2048; i += 256)
    ((float4*)W2Tl)[i] = ((const float4*)W2Tws)[i];

  const float4* u4 = (const float4*)u;
  const float4* v4 = (const float4*)v;
  const float4* at4 = (const float4*)attr;
  const float4* bt4 = (const float4*)BTws;

  const int nt = (E + 63) >> 6;
  for (int t = blockIdx.x; t < nt; t += gridDim.x) {
    const int e0 = t << 6;
    __syncthreads();

    if (tid < 64)       idxL[tid] = (e0 + tid < E) ? src[e0 + tid] : 0;
    else if (tid < 128) idxL[tid] = (e0 + tid - 64 < E) ? dst[e0 + tid - 64] : 0;
    if (tid < 128) outT[tid] = bm3[tid & 1];
    {
      int a0 = e0 * 4 + tid;
      float4 av = make_float4(0.f, 0.f, 0.f, 0.f);
      if (a0 < E * 4) av = at4[a0];
      ((float4*)attrL)[tid] = av;
    }
    float4 breg[16];
#pragma unroll
    for (int k = 0; k < 16; ++k) breg[k] = bt4[k * 32 + c4];
    __syncthreads();

#pragma unroll
    for (int it = 0; it < 8; ++it) {
      const int e = it * 8 + (tid >> 5);
      const int col = c4 * 4;
      float4 a = u4[(size_t)idxL[e] * 32 + c4];
      float4 b = v4[(size_t)idxL[64 + e] * 32 + c4];
      float sx = a.x + b.x, sy = a.y + b.y, sz = a.z + b.z, sw = a.w + b.w;
#pragma unroll
      for (int k = 0; k < 16; ++k) {
        float av = attrL[e * 16 + k];
        sx += av * breg[k].x; sy += av * breg[k].y;
        sz += av * breg[k].z; sw += av * breg[k].w;
      }
      float4 r;
      r.x = fmaxf(sx, 0.f); r.y = fmaxf(sy, 0.f);
      r.z = fmaxf(sz, 0.f); r.w = fmaxf(sw, 0.f);
      *(float4*)&Z1[e * 132 + col] = r;
    }
    __syncthreads();

    float acc[4][4];
#pragma unroll
    for (int c = 0; c < 4; ++c) {
      float bv = bm2[4 * tx + c];
#pragma unroll
      for (int i = 0; i < 4; ++i) acc[i][c] = bv;
    }
    for (int kk = 0; kk < 128; kk += 4) {
      float4 a[4], b[4];
#pragma unroll
      for (int i = 0; i < 4; ++i) a[i] = *(const float4*)&Z1[(4 * ty + i) * 132 + kk];
#pragma unroll
      for (int q = 0; q < 4; ++q) b[q] = *(const float4*)&W2Tl[(kk + q) * 64 + 4 * tx];
#pragma unroll
      for (int i = 0; i < 4; ++i) {
#pragma unroll
        for (int q = 0; q < 4; ++q) {
          float av = (q == 0) ? a[i].x : (q == 1) ? a[i].y : (q == 2) ? a[i].z : a[i].w;
          acc[i][0] += av * b[q].x;
          acc[i][1] += av * b[q].y;
          acc[i][2] += av * b[q].z;
          acc[i][3] += av * b[q].w;
        }
      }
    }

    float w30[4], w31[4];
#pragma unroll
    for (int c = 0; c < 4; ++c) {
      w30[c] = Wm3[4 * tx + c];
      w31[c] = Wm3[64 + 4 * tx + c];
    }
#pragma unroll
    for (int i = 0; i < 4; ++i) {
      float p0 = 0.f, p1 = 0.f;
#pragma unroll
      for (int c = 0; c < 4; ++c) {
        float z = fmaxf(acc[i][c], 0.f);
        p0 += z * w30[c];
        p1 += z * w31[c];
      }
      atomicAdd(&outT[(4 * ty + i) * 2 + 0], p0);
      atomicAdd(&outT[(4 * ty + i) * 2 + 1], p1);
    }
    __syncthreads();

    if (tid < 128) {
      int e = tid >> 1;
      if (e0 + e < E) out[(size_t)(e0 + e) * 2 + (tid & 1)] = outT[tid];
    }
  }
}

extern "C" void kernel_launch(void* const* d_in, const int* in_sizes, int n_in,
                              void* d_out, int out_size, void* d_ws, size_t ws_size,
                              hipStream_t stream) {
  const float* x    = (const float*)d_in[0];
  const int*   ei   = (const int*)d_in[1];
  const float* attr = (const float*)d_in[2];
  const float* W1l  = (const float*)d_in[3];
  const float* b1l  = (const float*)d_in[4];
  const float* W1r  = (const float*)d_in[5];
  const float* g1   = (const float*)d_in[6];
  const float* be1  = (const float*)d_in[7];
  const float* W2l  = (const float*)d_in[8];
  const float* b2l  = (const float*)d_in[9];
  const float* W2r  = (const float*)d_in[10];
  const float* g2   = (const float*)d_in[11];
  const float* be2  = (const float*)d_in[12];
  const float* Wm1  = (const float*)d_in[13];
  const float* bm1  = (const float*)d_in[14];
  const float* Wm2  = (const float*)d_in[15];
  const float* bm2  = (const float*)d_in[16];
  const float* Wm3  = (const float*)d_in[17];
  const float* bm3  = (const float*)d_in[18];
  float* out = (float*)d_out;

  const int N = in_sizes[0] / 128;
  const int E = in_sizes[1] / 2;
  const int* srcI = ei;
  const int* dstI = ei + E;

  float* ws = (float*)d_ws;
  const size_t NF = (size_t)N * 64;
  // five NF-sized float regions R0..R4 (overlaid across phases)
  float* R0 = ws;
  float* R1 = ws + NF;
  float* R2 = ws + 2 * NF;
  float* R3 = ws + 3 * NF;
  // R4 = ws + 4*NF (used only as second half of V)
  float* stats1 = ws + 5 * NF;    // 256
  float* stats2 = stats1 + 256;   // 256
  float* W2Tws  = stats2 + 256;   // 128*64
  float* BTws   = W2Tws + 8192;   // 16*128
  int*   rowptr = (int*)(BTws + 2048);   // N+1
  int*   cursor = rowptr + (N + 1);      // N
  int*   deg    = cursor + N;            // N
  int*   csrsrc = deg + N;               // E
  float* U = R1;                  // 2*NF (R1+R2)
  float* V = R3;                  // 2*NF (R3+R4)

  hipMemsetAsync(deg, 0, (size_t)N * sizeof(int), stream);
  hipMemsetAsync(stats1, 0, 512 * sizeof(float), stream);

  // ---- CSR build (per call; graph fixed within a call) ----
  const int eBlocks = (E + 255) / 256;
  k_hist<<<eBlocks, 256, 0, stream>>>(dstI, deg, E);
  k_scan<<<1, 1024, 0, stream>>>(deg, rowptr, cursor, N);
  k_fill<<<eBlocks, 256, 0, stream>>>(srcI, dstI, cursor, csrsrc, E);

  k_transpose<<<(64 * 128 + 255) / 256, 256, 0, stream>>>(Wm2, W2Tws, 64, 128);
  k_tbt<<<(16 * 128 + 255) / 256, 256, 0, stream>>>(Wm1, BTws);

  const int bnBlocks = (int)((NF + 255) / 256);

  // ---- conv1 ----
  k_lin<128><<<512, 256, 0, stream>>>(x, W1l, nullptr, R0, N);   // q1
  k_lin<128><<<512, 256, 0, stream>>>(x, W1r, b1l, R1, N);       // p1
  k_agg<<<512, 256, 0, stream>>>(R0, R1, rowptr, csrsrc, R2, stats1, N);  // hpre1
  k_finalize<<<1, 64, 0, stream>>>(stats1, N);
  k_bnrelu<<<bnBlocks, 256, 0, stream>>>(R2, stats1, g1, be1, R0, (int)NF);  // h1

  // ---- conv2 ----
  k_lin<64><<<512, 256, 0, stream>>>(R0, W2l, nullptr, R1, N);   // q2
  k_lin<64><<<512, 256, 0, stream>>>(R0, W2r, b2l, R2, N);       // p2
  k_agg<<<512, 256, 0, stream>>>(R1, R2, rowptr, csrsrc, R3, stats2, N);  // hpre2
  k_finalize<<<1, 64, 0, stream>>>(stats2, N);
  k_bnrelu<<<bnBlocks, 256, 0, stream>>>(R3, stats2, g2, be2, R0, (int)NF);  // h2

  // ---- per-node u/v for edge-MLP layer 1 ----
  k_lin2<<<1024, 256, 0, stream>>>(R0, Wm1, 0,  bm1,     U, N);  // u = A1*h2+bm1
  k_lin2<<<1024, 256, 0, stream>>>(R0, Wm1, 80, nullptr, V, N);  // v = C1*h2

  // ---- fused edge MLP ----
  k_edge<<<512, 256, 0, stream>>>(U, V, attr, srcI, dstI, W2Tws, BTws,
                                  bm2, Wm3, bm3, out, E);
}